// Round 6
// baseline (291.528 us; speedup 1.0000x reference)
//
#include <hip/hip_runtime.h>

// Problem constants (CausalSelfAttention: B=4 T=2048 C=768 H=KVH=6 D=128)
#define BB 4
#define TT 2048
#define CC 768
#define HH 6
#define DD 128
#define BT (BB * TT)          // 8192 rows
#define HALF 64
#define NBH (BB * HH)         // 24
// combined scale folded into q_t: exp(s/sqrt(128)) = exp2(s * QKSCALE)
#define QKSCALE 0.12753785627919282f   // (1/sqrt(128)) * log2(e)

typedef __bf16 v8bf __attribute__((ext_vector_type(8)));
typedef float f32x4 __attribute__((ext_vector_type(4)));

// ---------------- fp32 -> bf16 (RNE) ----------------
__device__ __forceinline__ unsigned short f2b(float f) {
  union { float f; unsigned u; } v; v.f = f;
  unsigned r = v.u + 0x7FFFu + ((v.u >> 16) & 1u);
  return (unsigned short)(r >> 16);
}
__device__ __forceinline__ float b2f(unsigned short u) {
  union { unsigned u; float f; } v; v.u = (unsigned)u << 16;
  return v.f;
}
// pack two fp32 -> bf16x2 by truncation: 1 v_perm_b32
__device__ __forceinline__ unsigned pk2(float f0, float f1) {
  union { float f; unsigned u; } a, b; a.f = f1; b.f = f0;
  return __builtin_amdgcn_perm(a.u, b.u, 0x07060302u);
}
// raw 2^x (v_exp_f32): inputs bounded (normed q/k), output feeds bf16
__device__ __forceinline__ float ex2(float x) {
  float r; asm("v_exp_f32 %0, %1" : "=v"(r) : "v"(x)); return r;
}

// async global->LDS, 16B per lane; lds base wave-uniform, deposit at base + lane*16
__device__ __forceinline__ void load_lds16(const void* g, void* l) {
  __builtin_amdgcn_global_load_lds(
      (const __attribute__((address_space(1))) unsigned int*)g,
      (__attribute__((address_space(3))) unsigned int*)(unsigned int)(unsigned long long)(l),
      16, 0, 0);
}

// ---------------- merged cvt: x (6144 blocks) + 4 weights (2304 blocks) -------
__global__ __launch_bounds__(256) void cvt_all_kernel(const float* __restrict__ x,
                                                      const float* __restrict__ w0,
                                                      const float* __restrict__ w1,
                                                      const float* __restrict__ w2,
                                                      const float* __restrict__ w3,
                                                      unsigned short* __restrict__ xb,
                                                      unsigned short* __restrict__ wb) {
  int bx = blockIdx.x;
  const float* src;
  unsigned short* dst;
  int i;
  if (bx < 6144) {
    src = x; dst = xb; i = bx * 256 + threadIdx.x;
  } else {
    int bsel = (bx - 6144) / 576;
    src = bsel == 0 ? w0 : bsel == 1 ? w1 : bsel == 2 ? w2 : w3;
    dst = wb + bsel * 589824;
    i = ((bx - 6144) % 576) * 256 + threadIdx.x;
  }
  float4 f = ((const float4*)src)[i];
  ushort4 o;
  o.x = f2b(f.x); o.y = f2b(f.y); o.z = f2b(f.z); o.w = f2b(f.w);
  ((ushort4*)dst)[i] = o;
}

// ---------------- fused QKV GEMM (128x128 tile, BK=32, dbuf + swizzled LDS) ----
// grid (64, 18): wsel = by/6 (0=q,1=k,2=v), head h = by%6.
// q,k -> bf16 [bh][t][d] (rope runs in place); v -> bf16 v_t [bh][d][t].
__global__ __launch_bounds__(256) void gemm_qkv(const unsigned short* __restrict__ A,
                                                const unsigned short* __restrict__ Wall,
                                                unsigned short* __restrict__ qb,
                                                unsigned short* __restrict__ kb,
                                                unsigned short* __restrict__ vt) {
  __shared__ __align__(16) unsigned short As[2][512 * 8];
  __shared__ __align__(16) unsigned short Bs[2][512 * 8];
  const int m0 = blockIdx.x * 128;
  const int wsel = blockIdx.y / HH, h = blockIdx.y % HH;
  const unsigned short* W = Wall + (size_t)wsel * 589824 + (size_t)h * 128 * CC;
  const int tid = threadIdx.x;
  const int wave = tid >> 6, lane = tid & 63;
  const int fr = lane & 15, quad = lane >> 4;
  const int wm = (wave & 1) * 64, wn = (wave >> 1) * 64;

  f32x4 acc[4][4];
#pragma unroll
  for (int i = 0; i < 4; i++)
#pragma unroll
    for (int j = 0; j < 4; j++) acc[i][j] = (f32x4){0.f, 0.f, 0.f, 0.f};

  auto stage = [&](int kk, int buf) {
#pragma unroll
    for (int it = 0; it < 2; it++) {
      int base_slot = wave * 128 + it * 64;
      int sigma = base_slot + lane;
      int r = sigma >> 2, g = (sigma & 3) ^ ((r >> 1) & 3);
      load_lds16(A + (size_t)(m0 + r) * CC + kk + g * 8, &As[buf][base_slot * 8]);
      load_lds16(W + (size_t)r * CC + kk + g * 8, &Bs[buf][base_slot * 8]);
    }
  };

  stage(0, 0);
  __syncthreads();
  for (int step = 0; step < CC / 32; step++) {
    int buf = step & 1;
    if (step + 1 < CC / 32) stage((step + 1) * 32, buf ^ 1);
    v8bf af[4], bfr[4];
#pragma unroll
    for (int i = 0; i < 4; i++) {
      int ra = wm + i * 16 + fr;
      af[i] = *(const v8bf*)&As[buf][(4 * ra + (quad ^ ((ra >> 1) & 3))) * 8];
      int rb = wn + i * 16 + fr;
      bfr[i] = *(const v8bf*)&Bs[buf][(4 * rb + (quad ^ ((rb >> 1) & 3))) * 8];
    }
#pragma unroll
    for (int i = 0; i < 4; i++)
#pragma unroll
      for (int j = 0; j < 4; j++)
        acc[i][j] = __builtin_amdgcn_mfma_f32_16x16x32_bf16(af[i], bfr[j], acc[i][j], 0, 0, 0);
    __syncthreads();
  }

  if (wsel < 2) {
    unsigned short* dst = wsel ? kb : qb;
#pragma unroll
    for (int i = 0; i < 4; i++) {
      int rr0 = m0 + wm + i * 16 + quad * 4;
      int b = rr0 >> 11, t0 = rr0 & 2047;
      size_t base = ((size_t)(b * HH + h) * TT + t0) * DD;
#pragma unroll
      for (int j = 0; j < 4; j++) {
        int d = wn + j * 16 + fr;
#pragma unroll
        for (int r = 0; r < 4; r++)
          dst[base + (size_t)r * DD + d] = f2b(acc[i][j][r]);
      }
    }
  } else {
#pragma unroll
    for (int i = 0; i < 4; i++) {
      int rr0 = m0 + wm + i * 16 + quad * 4;
      int b = rr0 >> 11, t0 = rr0 & 2047;
      int bh = b * HH + h;
#pragma unroll
      for (int j = 0; j < 4; j++) {
        int d = wn + j * 16 + fr;
        ushort4 u = { f2b(acc[i][j][0]), f2b(acc[i][j][1]),
                      f2b(acc[i][j][2]), f2b(acc[i][j][3]) };
        *(ushort4*)&vt[((size_t)bh * DD + d) * TT + t0] = u;
      }
    }
  }
}

// ---------------- wproj GEMM: 64x128 tile (768 blocks -> 3/CU) ----------------
__global__ __launch_bounds__(256) void gemm_w64(const unsigned short* __restrict__ A,
                                                const unsigned short* __restrict__ W,
                                                float* __restrict__ C) {
  __shared__ __align__(16) unsigned short As[2][256 * 8];
  __shared__ __align__(16) unsigned short Bs[2][512 * 8];
  const int m0 = blockIdx.x * 64, n0 = blockIdx.y * 128;
  const int tid = threadIdx.x;
  const int wave = tid >> 6, lane = tid & 63;
  const int fr = lane & 15, quad = lane >> 4;
  const int wm = (wave & 1) * 32, wn = (wave >> 1) * 64;

  f32x4 acc[2][4];
#pragma unroll
  for (int i = 0; i < 2; i++)
#pragma unroll
    for (int j = 0; j < 4; j++) acc[i][j] = (f32x4){0.f, 0.f, 0.f, 0.f};

  auto stage = [&](int kk, int buf) {
    {
      int base_slot = wave * 64;
      int sigma = base_slot + lane;
      int r = sigma >> 2, g = (sigma & 3) ^ ((r >> 1) & 3);
      load_lds16(A + (size_t)(m0 + r) * CC + kk + g * 8, &As[buf][base_slot * 8]);
    }
#pragma unroll
    for (int it = 0; it < 2; it++) {
      int base_slot = wave * 128 + it * 64;
      int sigma = base_slot + lane;
      int r = sigma >> 2, g = (sigma & 3) ^ ((r >> 1) & 3);
      load_lds16(W + (size_t)(n0 + r) * CC + kk + g * 8, &Bs[buf][base_slot * 8]);
    }
  };

  stage(0, 0);
  __syncthreads();
  for (int step = 0; step < CC / 32; step++) {
    int buf = step & 1;
    if (step + 1 < CC / 32) stage((step + 1) * 32, buf ^ 1);
    v8bf af[2], bfr[4];
#pragma unroll
    for (int i = 0; i < 2; i++) {
      int ra = wm + i * 16 + fr;
      af[i] = *(const v8bf*)&As[buf][(4 * ra + (quad ^ ((ra >> 1) & 3))) * 8];
    }
#pragma unroll
    for (int j = 0; j < 4; j++) {
      int rb = wn + j * 16 + fr;
      bfr[j] = *(const v8bf*)&Bs[buf][(4 * rb + (quad ^ ((rb >> 1) & 3))) * 8];
    }
#pragma unroll
    for (int i = 0; i < 2; i++)
#pragma unroll
      for (int j = 0; j < 4; j++)
        acc[i][j] = __builtin_amdgcn_mfma_f32_16x16x32_bf16(af[i], bfr[j], acc[i][j], 0, 0, 0);
    __syncthreads();
  }

  const int orow = m0 + wm + quad * 4;
#pragma unroll
  for (int i = 0; i < 2; i++)
#pragma unroll
    for (int j = 0; j < 4; j++) {
      int oc = n0 + wn + j * 16 + fr;
#pragma unroll
      for (int r = 0; r < 4; r++)
        C[(size_t)(orow + i * 16 + r) * CC + oc] = acc[i][j][r];
    }
}

// ---------------- RoPE + sample-var norm, in place, q and k in one launch -----
__global__ __launch_bounds__(256) void rope_all_kernel(unsigned short* __restrict__ qb,
                                                       unsigned short* __restrict__ kb,
                                                       const float* __restrict__ cosb,
                                                       const float* __restrict__ sinb) {
  int bx = blockIdx.x;
  unsigned short* qk = (bx < 12288) ? qb : kb;
  float scale = (bx < 12288) ? QKSCALE : 1.0f;
  int idx = (bx % 12288) * 4 + (threadIdx.x >> 6);   // bh*T + t
  int lane = threadIdx.x & 63;
  int tpos = idx & (TT - 1);
  size_t base = (size_t)idx * DD;

  float x1 = b2f(qk[base + lane]);
  float x2 = b2f(qk[base + HALF + lane]);
  float c = cosb[tpos * HALF + lane];
  float s = sinb[tpos * HALF + lane];
  float o1 = x1 * c + x2 * s;
  float o2 = x2 * c - x1 * s;

  float sum = o1 + o2;
#pragma unroll
  for (int off = 32; off; off >>= 1) sum += __shfl_xor(sum, off);
  float mean = sum * (1.f / 128.f);
  float d1 = o1 - mean, d2 = o2 - mean;
  float vs = d1 * d1 + d2 * d2;
#pragma unroll
  for (int off = 32; off; off >>= 1) vs += __shfl_xor(vs, off);
  float inv = scale / (sqrtf(vs * (1.f / 127.f)) + 1e-6f);

  qk[base + lane] = f2b(d1 * inv);
  qk[base + HALF + lane] = f2b(d2 * inv);
}

// ---------------- MFMA flash attention v9: V direct-from-L2, K-only LDS ------
// R5 lesson: doubling occupancy left dur flat -> per-CU LDS pipe saturated
// (64KB frag reads + 16KB staging per block-iter + 4.8M conflict-cycles).
// v9 removes V from LDS: the V-frag a lane needs is v_t[bh][nt2*16+fr]
// [j0+quad*8..+7] -- 16B contiguous, wave-invariant -> direct global load
// (saddr+voffset). V is L2-resident (per-head 512KB pinned to one XCD;
// grid idx = uu*24+bh = bh mod 8) and the 4 barrier-synced waves read the
// same addresses -> L1 absorbs the 4x redundancy. LDS traffic -60%, V bank
// conflicts gone, LDS 16KB. V loads issue before the QK MFMA cluster ->
// ~300cyc of QK+softmax hides L2 latency. exp2f -> raw v_exp_f32 (saves
// ~50-80 VALU/iter of libm). Everything else byte-identical to v8.
__global__ __launch_bounds__(256) void attn_mfma(const unsigned short* __restrict__ qtb,
                                                 const unsigned short* __restrict__ ktb,
                                                 const unsigned short* __restrict__ vtb,
                                                 unsigned short* __restrict__ Opart,
                                                 float* __restrict__ lpart) {
  __shared__ __align__(16) unsigned short Ks[2][512 * 8];   // 32 x 128 bf16 (dbuf)

  const int u = blockIdx.x;
  const int bh = u % NBH;
  const int uu = u / NBH;                         // 0..79, full-16 chunks first
  int qb, c;
  if (uu < 25)       { c = 0; qb = 31 - uu; }
  else if (uu < 42)  { c = 1; qb = 31 - (uu - 25); }
  else if (uu < 51)  { c = 2; qb = 31 - (uu - 42); }
  else if (uu == 51) { c = 3; qb = 31; }
  else { int uu2 = uu - 52; int sidx = uu2 >> 2; c = uu2 & 3; qb = 8 * c + 6 - sidx; }
  const int t0 = c * 16;                          // 32-row K/V tiles
  const int t1 = min(t0 + 16, 2 * qb + 2);
  const int niter = t1 - t0;

  const int tid = threadIdx.x;
  const int wave = tid >> 6, lane = tid & 63;
  const int fr = lane & 15, quad = lane >> 4;
  const int idxf = 4 * ((quad & 1) * 32 + fr);    // bpermute byte idx, first src quad
  const int idxs = idxf + 64;                     // second src quad (+16 lanes)
  const size_t head_base = (size_t)bh * TT * DD;
  const int m0 = qb * 64 + wave * 16;             // wave's 16 Q rows

  v8bf qf[4];
#pragma unroll
  for (int kbk = 0; kbk < 4; kbk++)
    qf[kbk] = *(const v8bf*)(qtb + head_base +
                             (size_t)(m0 + fr) * DD + kbk * 32 + quad * 8);

  const __bf16 one_bf = (__bf16)1.0f;
  v8bf ones = {one_bf, one_bf, one_bf, one_bf, one_bf, one_bf, one_bf, one_bf};

  f32x4 oacc[8];
#pragma unroll
  for (int i = 0; i < 8; i++) oacc[i] = (f32x4){0.f, 0.f, 0.f, 0.f};
  f32x4 lacc = (f32x4){0.f, 0.f, 0.f, 0.f};

  // K staging: per-lane global/LDS offsets precomputed (2 slots per lane)
  const unsigned short* khead = ktb + head_base;
  int sg0 = wave * 64 + lane;                     // slot sigma, it2=0
  int sg1 = 256 + wave * 64 + lane;               // it2=1
  const int kg0 = (sg0 >> 4) * DD + (((sg0 & 15) ^ ((sg0 >> 4) & 7)) * 8);
  const int kg1 = (sg1 >> 4) * DD + (((sg1 & 15) ^ ((sg1 >> 4) & 7)) * 8);
  unsigned short* ks0a = &Ks[0][sg0 * 8];
  unsigned short* ks1a = &Ks[0][sg1 * 8];
  unsigned short* ks0b = &Ks[1][sg0 * 8];
  unsigned short* ks1b = &Ks[1][sg1 * 8];

  // V direct loads: per-lane element offset into vtb+head_base
  const unsigned short* vhead = vtb + head_base;
  const unsigned vbase0 = (unsigned)(fr * TT + t0 * 32 + quad * 8);

  auto stageK = [&](int jt, int buf) {
    const unsigned short* kb2 = khead + (size_t)(jt * 32) * DD;
    load_lds16(kb2 + kg0, buf ? ks0b : ks0a);
    load_lds16(kb2 + kg1, buf ? ks1b : ks1a);
  };

  stageK(t0, 0);
  __syncthreads();

  for (int it = 0; it < niter; it++) {
    const int jt = t0 + it;
    const int buf = it & 1;
    if (it + 1 < niter) stageK(jt + 1, buf ^ 1);

    const int j0 = jt * 32;
    if (j0 <= m0 + 15) {             // wave has unmasked rows (uniform branch)
      // V frags for this tile: direct global (L1/L2), issued before QK MFMAs
      v8bf vf[8];
      {
        const unsigned vo = vbase0 + (unsigned)(it * 32);
#pragma unroll
        for (int nt2 = 0; nt2 < 8; nt2++)
          vf[nt2] = *(const v8bf*)&vhead[vo + (unsigned)(nt2 * 16 * TT)];
      }

      // S^T: D[m = K-col][n = Q-row], one 16x32 tile per wave
      f32x4 st0 = (f32x4){0.f, 0.f, 0.f, 0.f};
      f32x4 st1 = (f32x4){0.f, 0.f, 0.f, 0.f};
      __builtin_amdgcn_s_setprio(1);
#pragma unroll
      for (int kbk = 0; kbk < 4; kbk++) {
        int g = 4 * kbk + quad;
        int gx = (g ^ (fr & 7)) * 8;
        v8bf a0 = *(const v8bf*)&Ks[buf][(16 * fr) * 8 + gx];
        v8bf a1 = *(const v8bf*)&Ks[buf][(16 * (fr + 16)) * 8 + gx];
        st0 = __builtin_amdgcn_mfma_f32_16x16x32_bf16(a0, qf[kbk], st0, 0, 0, 0);
        st1 = __builtin_amdgcn_mfma_f32_16x16x32_bf16(a1, qf[kbk], st1, 0, 0, 0);
      }
      __builtin_amdgcn_s_setprio(0);

      const bool diag = (j0 + 31 > m0);
      float p[8];
      if (diag) {
        const int qrow = m0 + fr;
#pragma unroll
        for (int r = 0; r < 4; r++) {
          int c0 = j0 + quad * 4 + r;
          p[r]     = (c0      <= qrow) ? ex2(st0[r]) : 0.f;
          p[4 + r] = (c0 + 16 <= qrow) ? ex2(st1[r]) : 0.f;
        }
      } else {
#pragma unroll
        for (int r = 0; r < 4; r++) { p[r] = ex2(st0[r]); p[4 + r] = ex2(st1[r]); }
      }
      // packed words: A0={c0,c1} A1={c2,c3} (cols 0-15 over quads); B = cols 16-31
      unsigned A0 = pk2(p[0], p[1]), A1 = pk2(p[2], p[3]);
      unsigned B0 = pk2(p[4], p[5]), B1 = pk2(p[6], p[7]);
      unsigned alo0 = (unsigned)__builtin_amdgcn_ds_bpermute(idxf, (int)A0);
      unsigned alo1 = (unsigned)__builtin_amdgcn_ds_bpermute(idxf, (int)A1);
      unsigned ahi0 = (unsigned)__builtin_amdgcn_ds_bpermute(idxs, (int)A0);
      unsigned ahi1 = (unsigned)__builtin_amdgcn_ds_bpermute(idxs, (int)A1);
      unsigned blo0 = (unsigned)__builtin_amdgcn_ds_bpermute(idxf, (int)B0);
      unsigned blo1 = (unsigned)__builtin_amdgcn_ds_bpermute(idxf, (int)B1);
      unsigned bhi0 = (unsigned)__builtin_amdgcn_ds_bpermute(idxs, (int)B0);
      unsigned bhi1 = (unsigned)__builtin_amdgcn_ds_bpermute(idxs, (int)B1);
      const bool ql = (quad < 2);
      union { unsigned w[4]; v8bf v; } pw;
      pw.w[0] = ql ? alo0 : blo0;
      pw.w[1] = ql ? alo1 : blo1;
      pw.w[2] = ql ? ahi0 : bhi0;
      pw.w[3] = ql ? ahi1 : bhi1;
      v8bf pa = pw.v;

      // PV + l (V from registers)
      __builtin_amdgcn_s_setprio(1);
#pragma unroll
      for (int nt2 = 0; nt2 < 8; nt2++)
        oacc[nt2] = __builtin_amdgcn_mfma_f32_16x16x32_bf16(pa, vf[nt2], oacc[nt2], 0, 0, 0);
      lacc = __builtin_amdgcn_mfma_f32_16x16x32_bf16(pa, ones, lacc, 0, 0, 0);
      __builtin_amdgcn_s_setprio(0);
    }
    __syncthreads();
  }

  // partial write: rows m0 + quad*4 + r, col d = nt2*16 + fr
  unsigned short* Oc = Opart + (size_t)c * (NBH * TT * DD) + head_base;
#pragma unroll
  for (int nt2 = 0; nt2 < 8; nt2++)
#pragma unroll
    for (int r = 0; r < 4; r++)
      Oc[(size_t)(m0 + quad * 4 + r) * DD + nt2 * 16 + fr] = f2b(oacc[nt2][r]);
  if (fr == 0) {
#pragma unroll
    for (int r = 0; r < 4; r++)
      lpart[c * (NBH * TT) + bh * TT + m0 + quad * 4 + r] = lacc[r];
  }
}

// ---------------- combine: yb = (sum_c O_c)/(sum_c l_c), bf16 [bt][C] ----------
__global__ __launch_bounds__(256) void combine_kernel(const unsigned short* __restrict__ Opart,
                                                      const float* __restrict__ lpart,
                                                      unsigned short* __restrict__ yb) {
  int idx = blockIdx.x * 256 + threadIdx.x;    // 1,572,864 threads, 4 elems each
  int row = idx >> 5;                          // bh*2048 + t
  int dg = (idx & 31) * 4;
  int t = row & 2047;
  int qt = t >> 7;                             // 128-row blocks
  int nc = (4 * qt + 4 + 15) >> 4;             // chunks written for this row

  float a0 = 0.f, a1 = 0.f, a2 = 0.f, a3 = 0.f, l = 0.f;
  for (int cchunk = 0; cchunk < nc; cchunk++) {
    ushort4 o = *(const ushort4*)&Opart[(size_t)cchunk * (NBH * TT * DD) + (size_t)row * DD + dg];
    a0 += b2f(o.x); a1 += b2f(o.y); a2 += b2f(o.z); a3 += b2f(o.w);
    l += lpart[cchunk * (NBH * TT) + row];
  }
  float linv = 1.f / l;
  int bh = row >> 11;
  int b = bh / HH, h = bh % HH;
  ushort4 uo = { f2b(a0 * linv), f2b(a1 * linv), f2b(a2 * linv), f2b(a3 * linv) };
  *(ushort4*)&yb[((size_t)(b * TT + t)) * CC + h * DD + dg] = uo;
}

// ---------------- launch ----------------
extern "C" void kernel_launch(void* const* d_in, const int* in_sizes, int n_in,
                              void* d_out, int out_size, void* d_ws, size_t ws_size,
                              hipStream_t stream) {
  const float* x     = (const float*)d_in[0];
  const float* cosb  = (const float*)d_in[1];
  const float* sinb  = (const float*)d_in[2];
  const float* wq    = (const float*)d_in[3];
  const float* wk    = (const float*)d_in[4];
  const float* wv    = (const float*)d_in[5];
  const float* wproj = (const float*)d_in[6];
  float* out = (float*)d_out;

  // workspace layout (117,964,800 B exactly):
  //   0         : q_t bf16 [bh][t][d] (12,582,912)
  //   12582912  : k_t bf16 [bh][t][d] (12,582,912)
  //   25165824  : v_t bf16 [bh][d][t] (12,582,912)
  //   37748736  : yb  bf16 [bt][C]    (12,582,912)
  //   50331648  : xb  bf16 (12,582,912) -> dead after gemm_qkv -> lpart (786,432)
  //   62914560  : wb  bf16 4x589824 elems (4,718,592)
  //   67633152  : Opart bf16 4 chunks x [bh][t][d] (50,331,648)
  char* w = (char*)d_ws;
  unsigned short* q_t   = (unsigned short*)(w);
  unsigned short* k_t   = (unsigned short*)(w + 12582912);
  unsigned short* v_t   = (unsigned short*)(w + 25165824);
  unsigned short* yb    = (unsigned short*)(w + 37748736);
  unsigned short* xb    = (unsigned short*)(w + 50331648);
  float*          lpart = (float*)(w + 50331648);   // alias xb (dead after gemm_qkv)
  unsigned short* wb    = (unsigned short*)(w + 62914560);
  unsigned short* Opart = (unsigned short*)(w + 67633152);

  cvt_all_kernel<<<8448, 256, 0, stream>>>(x, wq, wk, wv, wproj, xb, wb);

  gemm_qkv<<<dim3(BT / 128, 3 * HH), 256, 0, stream>>>(xb, wb, q_t, k_t, v_t);

  rope_all_kernel<<<24576, 256, 0, stream>>>(q_t, k_t, cosb, sinb);

  attn_mfma<<<1920, 256, 0, stream>>>(q_t, k_t, v_t, Opart, lpart);
  combine_kernel<<<6144, 256, 0, stream>>>(Opart, lpart, yb);

  gemm_w64<<<dim3(BT / 64, CC / 128), 256, 0, stream>>>(yb, wb + 3 * 589824, out);
}

// Round 7
// 240.553 us; speedup vs baseline: 1.2119x; 1.2119x over previous
//
#include <hip/hip_runtime.h>

// Problem constants (CausalSelfAttention: B=4 T=2048 C=768 H=KVH=6 D=128)
#define BB 4
#define TT 2048
#define CC 768
#define HH 6
#define DD 128
#define BT (BB * TT)          // 8192 rows
#define HALF 64
#define NBH (BB * HH)         // 24
// combined scale folded into q_t: exp(s/sqrt(128)) = exp2(s * QKSCALE)
#define QKSCALE 0.12753785627919282f   // (1/sqrt(128)) * log2(e)

typedef __bf16 v8bf __attribute__((ext_vector_type(8)));
typedef float f32x4 __attribute__((ext_vector_type(4)));

// ---------------- fp32 -> bf16 (RNE) ----------------
__device__ __forceinline__ unsigned short f2b(float f) {
  union { float f; unsigned u; } v; v.f = f;
  unsigned r = v.u + 0x7FFFu + ((v.u >> 16) & 1u);
  return (unsigned short)(r >> 16);
}
__device__ __forceinline__ float b2f(unsigned short u) {
  union { unsigned u; float f; } v; v.u = (unsigned)u << 16;
  return v.f;
}
// pack two fp32 -> bf16x2 by truncation: 1 v_perm_b32
__device__ __forceinline__ unsigned pk2(float f0, float f1) {
  union { float f; unsigned u; } a, b; a.f = f1; b.f = f0;
  return __builtin_amdgcn_perm(a.u, b.u, 0x07060302u);
}
// raw 2^x (v_exp_f32): inputs bounded (normed q/k), output feeds bf16
__device__ __forceinline__ float ex2(float x) {
  float r; asm("v_exp_f32 %0, %1" : "=v"(r) : "v"(x)); return r;
}

// async global->LDS, 16B per lane; lds base wave-uniform, deposit at base + lane*16
__device__ __forceinline__ void load_lds16(const void* g, void* l) {
  __builtin_amdgcn_global_load_lds(
      (const __attribute__((address_space(1))) unsigned int*)g,
      (__attribute__((address_space(3))) unsigned int*)(unsigned int)(unsigned long long)(l),
      16, 0, 0);
}

// ---------------- merged cvt: x (6144 blocks) + 4 weights (2304 blocks) -------
__global__ __launch_bounds__(256) void cvt_all_kernel(const float* __restrict__ x,
                                                      const float* __restrict__ w0,
                                                      const float* __restrict__ w1,
                                                      const float* __restrict__ w2,
                                                      const float* __restrict__ w3,
                                                      unsigned short* __restrict__ xb,
                                                      unsigned short* __restrict__ wb) {
  int bx = blockIdx.x;
  const float* src;
  unsigned short* dst;
  int i;
  if (bx < 6144) {
    src = x; dst = xb; i = bx * 256 + threadIdx.x;
  } else {
    int bsel = (bx - 6144) / 576;
    src = bsel == 0 ? w0 : bsel == 1 ? w1 : bsel == 2 ? w2 : w3;
    dst = wb + bsel * 589824;
    i = ((bx - 6144) % 576) * 256 + threadIdx.x;
  }
  float4 f = ((const float4*)src)[i];
  ushort4 o;
  o.x = f2b(f.x); o.y = f2b(f.y); o.z = f2b(f.z); o.w = f2b(f.w);
  ((ushort4*)dst)[i] = o;
}

// ---------------- fused QKV GEMM (128x128 tile, BK=32, dbuf + swizzled LDS) ----
// grid (64, 18): wsel = by/6 (0=q,1=k,2=v), head h = by%6.
// q,k -> bf16 [bh][t][d] (rope runs in place).
// v -> repacked PV-fragment order: V2[bh][jt][nt2][lane][8] (lane=qv*16+(d&15),
// elem j: holds V[t=jt*32+qv*8+j][d=nt2*16+(d&15)]) so the attn PV B-operand
// load is lane-contiguous (1KB coalesced per wave instruction).
__global__ __launch_bounds__(256) void gemm_qkv(const unsigned short* __restrict__ A,
                                                const unsigned short* __restrict__ Wall,
                                                unsigned short* __restrict__ qb,
                                                unsigned short* __restrict__ kb,
                                                unsigned short* __restrict__ vt) {
  __shared__ __align__(16) unsigned short As[2][512 * 8];
  __shared__ __align__(16) unsigned short Bs[2][512 * 8];
  const int m0 = blockIdx.x * 128;
  const int wsel = blockIdx.y / HH, h = blockIdx.y % HH;
  const unsigned short* W = Wall + (size_t)wsel * 589824 + (size_t)h * 128 * CC;
  const int tid = threadIdx.x;
  const int wave = tid >> 6, lane = tid & 63;
  const int fr = lane & 15, quad = lane >> 4;
  const int wm = (wave & 1) * 64, wn = (wave >> 1) * 64;

  f32x4 acc[4][4];
#pragma unroll
  for (int i = 0; i < 4; i++)
#pragma unroll
    for (int j = 0; j < 4; j++) acc[i][j] = (f32x4){0.f, 0.f, 0.f, 0.f};

  auto stage = [&](int kk, int buf) {
#pragma unroll
    for (int it = 0; it < 2; it++) {
      int base_slot = wave * 128 + it * 64;
      int sigma = base_slot + lane;
      int r = sigma >> 2, g = (sigma & 3) ^ ((r >> 1) & 3);
      load_lds16(A + (size_t)(m0 + r) * CC + kk + g * 8, &As[buf][base_slot * 8]);
      load_lds16(W + (size_t)r * CC + kk + g * 8, &Bs[buf][base_slot * 8]);
    }
  };

  stage(0, 0);
  __syncthreads();
  for (int step = 0; step < CC / 32; step++) {
    int buf = step & 1;
    if (step + 1 < CC / 32) stage((step + 1) * 32, buf ^ 1);
    v8bf af[4], bfr[4];
#pragma unroll
    for (int i = 0; i < 4; i++) {
      int ra = wm + i * 16 + fr;
      af[i] = *(const v8bf*)&As[buf][(4 * ra + (quad ^ ((ra >> 1) & 3))) * 8];
      int rb = wn + i * 16 + fr;
      bfr[i] = *(const v8bf*)&Bs[buf][(4 * rb + (quad ^ ((rb >> 1) & 3))) * 8];
    }
#pragma unroll
    for (int i = 0; i < 4; i++)
#pragma unroll
      for (int j = 0; j < 4; j++)
        acc[i][j] = __builtin_amdgcn_mfma_f32_16x16x32_bf16(af[i], bfr[j], acc[i][j], 0, 0, 0);
    __syncthreads();
  }

  if (wsel < 2) {
    unsigned short* dst = wsel ? kb : qb;
#pragma unroll
    for (int i = 0; i < 4; i++) {
      int rr0 = m0 + wm + i * 16 + quad * 4;
      int b = rr0 >> 11, t0 = rr0 & 2047;
      size_t base = ((size_t)(b * HH + h) * TT + t0) * DD;
#pragma unroll
      for (int j = 0; j < 4; j++) {
        int d = wn + j * 16 + fr;
#pragma unroll
        for (int r = 0; r < 4; r++)
          dst[base + (size_t)r * DD + d] = f2b(acc[i][j][r]);
      }
    }
  } else {
#pragma unroll
    for (int i = 0; i < 4; i++) {
      int rr0 = m0 + wm + i * 16 + quad * 4;
      int b = rr0 >> 11, t0_ = rr0 & 2047;
      int bh = b * HH + h;
      int jt = t0_ >> 5;              // 32-row V tile
      int qv = (t0_ >> 3) & 3;        // quad slot within tile (const over r)
      int jj = t0_ & 7;               // elem start within lane group (0 or 4)
#pragma unroll
      for (int j = 0; j < 4; j++) {
        int d = wn + j * 16 + fr;
        int lane_v = qv * 16 + (d & 15);
        size_t off = ((size_t)(bh * 64 + jt) * 8 + (d >> 4)) * 512 + lane_v * 8 + jj;
        ushort4 u = { f2b(acc[i][j][0]), f2b(acc[i][j][1]),
                      f2b(acc[i][j][2]), f2b(acc[i][j][3]) };
        *(ushort4*)&vt[off] = u;
      }
    }
  }
}

// ---------------- wproj GEMM: 64x128 tile (768 blocks -> 3/CU) ----------------
__global__ __launch_bounds__(256) void gemm_w64(const unsigned short* __restrict__ A,
                                                const unsigned short* __restrict__ W,
                                                float* __restrict__ C) {
  __shared__ __align__(16) unsigned short As[2][256 * 8];
  __shared__ __align__(16) unsigned short Bs[2][512 * 8];
  const int m0 = blockIdx.x * 64, n0 = blockIdx.y * 128;
  const int tid = threadIdx.x;
  const int wave = tid >> 6, lane = tid & 63;
  const int fr = lane & 15, quad = lane >> 4;
  const int wm = (wave & 1) * 32, wn = (wave >> 1) * 64;

  f32x4 acc[2][4];
#pragma unroll
  for (int i = 0; i < 2; i++)
#pragma unroll
    for (int j = 0; j < 4; j++) acc[i][j] = (f32x4){0.f, 0.f, 0.f, 0.f};

  auto stage = [&](int kk, int buf) {
    {
      int base_slot = wave * 64;
      int sigma = base_slot + lane;
      int r = sigma >> 2, g = (sigma & 3) ^ ((r >> 1) & 3);
      load_lds16(A + (size_t)(m0 + r) * CC + kk + g * 8, &As[buf][base_slot * 8]);
    }
#pragma unroll
    for (int it = 0; it < 2; it++) {
      int base_slot = wave * 128 + it * 64;
      int sigma = base_slot + lane;
      int r = sigma >> 2, g = (sigma & 3) ^ ((r >> 1) & 3);
      load_lds16(W + (size_t)(n0 + r) * CC + kk + g * 8, &Bs[buf][base_slot * 8]);
    }
  };

  stage(0, 0);
  __syncthreads();
  for (int step = 0; step < CC / 32; step++) {
    int buf = step & 1;
    if (step + 1 < CC / 32) stage((step + 1) * 32, buf ^ 1);
    v8bf af[2], bfr[4];
#pragma unroll
    for (int i = 0; i < 2; i++) {
      int ra = wm + i * 16 + fr;
      af[i] = *(const v8bf*)&As[buf][(4 * ra + (quad ^ ((ra >> 1) & 3))) * 8];
    }
#pragma unroll
    for (int j = 0; j < 4; j++) {
      int rb = wn + j * 16 + fr;
      bfr[j] = *(const v8bf*)&Bs[buf][(4 * rb + (quad ^ ((rb >> 1) & 3))) * 8];
    }
#pragma unroll
    for (int i = 0; i < 2; i++)
#pragma unroll
      for (int j = 0; j < 4; j++)
        acc[i][j] = __builtin_amdgcn_mfma_f32_16x16x32_bf16(af[i], bfr[j], acc[i][j], 0, 0, 0);
    __syncthreads();
  }

  const int orow = m0 + wm + quad * 4;
#pragma unroll
  for (int i = 0; i < 2; i++)
#pragma unroll
    for (int j = 0; j < 4; j++) {
      int oc = n0 + wn + j * 16 + fr;
#pragma unroll
      for (int r = 0; r < 4; r++)
        C[(size_t)(orow + i * 16 + r) * CC + oc] = acc[i][j][r];
    }
}

// ---------------- RoPE + sample-var norm, in place, q and k in one launch -----
__global__ __launch_bounds__(256) void rope_all_kernel(unsigned short* __restrict__ qb,
                                                       unsigned short* __restrict__ kb,
                                                       const float* __restrict__ cosb,
                                                       const float* __restrict__ sinb) {
  int bx = blockIdx.x;
  unsigned short* qk = (bx < 12288) ? qb : kb;
  float scale = (bx < 12288) ? QKSCALE : 1.0f;
  int idx = (bx % 12288) * 4 + (threadIdx.x >> 6);   // bh*T + t
  int lane = threadIdx.x & 63;
  int tpos = idx & (TT - 1);
  size_t base = (size_t)idx * DD;

  float x1 = b2f(qk[base + lane]);
  float x2 = b2f(qk[base + HALF + lane]);
  float c = cosb[tpos * HALF + lane];
  float s = sinb[tpos * HALF + lane];
  float o1 = x1 * c + x2 * s;
  float o2 = x2 * c - x1 * s;

  float sum = o1 + o2;
#pragma unroll
  for (int off = 32; off; off >>= 1) sum += __shfl_xor(sum, off);
  float mean = sum * (1.f / 128.f);
  float d1 = o1 - mean, d2 = o2 - mean;
  float vs = d1 * d1 + d2 * d2;
#pragma unroll
  for (int off = 32; off; off >>= 1) vs += __shfl_xor(vs, off);
  float inv = scale / (sqrtf(vs * (1.f / 127.f)) + 1e-6f);

  qk[base + lane] = f2b(d1 * inv);
  qk[base + HALF + lane] = f2b(d2 * inv);
}

// ---------------- MFMA flash attention v10: coalesced V-from-L2, K-only LDS --
// R6 autopsy: V "direct" loads were 16-line gathers (fr*TT stride) AND issued
// after stageK so the PV wait drained the K prefetch (vmcnt 0). v10 fixes
// both: V is repacked by gemm_qkv into PV-fragment order so each wave V-load
// is 1KB lane-contiguous (8 lines), and V loads issue BEFORE stageK so the
// PV wait is a counted vmcnt(2) with K prefetch still in flight. Pipe balance
// per block-iter: LDS 80->40KB (K stage + K frags), TCP 16->40KB -- the two
// memory pipes now run in parallel. Everything else = R5's verified v8
// (16-row waves, KVBLK=32 dbuf, bpermute no-Ps, LPT grid 1920) + ex2.
__global__ __launch_bounds__(256) void attn_mfma(const unsigned short* __restrict__ qtb,
                                                 const unsigned short* __restrict__ ktb,
                                                 const unsigned short* __restrict__ vtb,
                                                 unsigned short* __restrict__ Opart,
                                                 float* __restrict__ lpart) {
  __shared__ __align__(16) unsigned short Ks[2][512 * 8];   // 32 x 128 bf16 (dbuf)

  const int u = blockIdx.x;
  const int bh = u % NBH;
  const int uu = u / NBH;                         // 0..79, full-16 chunks first
  int qb, c;
  if (uu < 25)       { c = 0; qb = 31 - uu; }
  else if (uu < 42)  { c = 1; qb = 31 - (uu - 25); }
  else if (uu < 51)  { c = 2; qb = 31 - (uu - 42); }
  else if (uu == 51) { c = 3; qb = 31; }
  else { int uu2 = uu - 52; int sidx = uu2 >> 2; c = uu2 & 3; qb = 8 * c + 6 - sidx; }
  const int t0 = c * 16;                          // 32-row K/V tiles
  const int t1 = min(t0 + 16, 2 * qb + 2);
  const int niter = t1 - t0;

  const int tid = threadIdx.x;
  const int wave = tid >> 6, lane = tid & 63;
  const int fr = lane & 15, quad = lane >> 4;
  const int idxf = 4 * ((quad & 1) * 32 + fr);    // bpermute byte idx, first src quad
  const int idxs = idxf + 64;                     // second src quad (+16 lanes)
  const size_t head_base = (size_t)bh * TT * DD;
  const int m0 = qb * 64 + wave * 16;             // wave's 16 Q rows

  v8bf qf[4];
#pragma unroll
  for (int kbk = 0; kbk < 4; kbk++)
    qf[kbk] = *(const v8bf*)(qtb + head_base +
                             (size_t)(m0 + fr) * DD + kbk * 32 + quad * 8);

  const __bf16 one_bf = (__bf16)1.0f;
  v8bf ones = {one_bf, one_bf, one_bf, one_bf, one_bf, one_bf, one_bf, one_bf};

  f32x4 oacc[8];
#pragma unroll
  for (int i = 0; i < 8; i++) oacc[i] = (f32x4){0.f, 0.f, 0.f, 0.f};
  f32x4 lacc = (f32x4){0.f, 0.f, 0.f, 0.f};

  // K staging: per-lane global/LDS offsets precomputed (2 slots per lane)
  const unsigned short* khead = ktb + head_base;
  int sg0 = wave * 64 + lane;                     // slot sigma, it2=0
  int sg1 = 256 + wave * 64 + lane;               // it2=1
  const int kg0 = (sg0 >> 4) * DD + (((sg0 & 15) ^ ((sg0 >> 4) & 7)) * 8);
  const int kg1 = (sg1 >> 4) * DD + (((sg1 & 15) ^ ((sg1 >> 4) & 7)) * 8);
  unsigned short* ks0a = &Ks[0][sg0 * 8];
  unsigned short* ks1a = &Ks[0][sg1 * 8];
  unsigned short* ks0b = &Ks[1][sg0 * 8];
  unsigned short* ks1b = &Ks[1][sg1 * 8];

  // V2 repacked: group (bh*64+jt)*8+nt2 of 512 elems; lane slice = lane*8
  const unsigned short* v2h = vtb + head_base;

  auto stageK = [&](int jt, int buf) {
    const unsigned short* kb2 = khead + (size_t)(jt * 32) * DD;
    load_lds16(kb2 + kg0, buf ? ks0b : ks0a);
    load_lds16(kb2 + kg1, buf ? ks1b : ks1a);
  };

  stageK(t0, 0);
  __syncthreads();

  for (int it = 0; it < niter; it++) {
    const int jt = t0 + it;
    const int buf = it & 1;
    const int j0 = jt * 32;
    const bool active = (j0 <= m0 + 15);   // wave-uniform

    // V frags first (coalesced 1KB/instr), so PV's wait leaves stageK in flight
    v8bf vf[8];
    if (active) {
      const unsigned short* vt2 = v2h + (size_t)(jt * 8) * 512 + lane * 8;
#pragma unroll
      for (int nt2 = 0; nt2 < 8; nt2++)
        vf[nt2] = *(const v8bf*)&vt2[nt2 * 512];
    }

    if (it + 1 < niter) stageK(jt + 1, buf ^ 1);

    if (active) {
      // S^T: D[m = K-col][n = Q-row], one 16x32 tile per wave
      f32x4 st0 = (f32x4){0.f, 0.f, 0.f, 0.f};
      f32x4 st1 = (f32x4){0.f, 0.f, 0.f, 0.f};
      __builtin_amdgcn_s_setprio(1);
#pragma unroll
      for (int kbk = 0; kbk < 4; kbk++) {
        int g = 4 * kbk + quad;
        int gx = (g ^ (fr & 7)) * 8;
        v8bf a0 = *(const v8bf*)&Ks[buf][(16 * fr) * 8 + gx];
        v8bf a1 = *(const v8bf*)&Ks[buf][(16 * (fr + 16)) * 8 + gx];
        st0 = __builtin_amdgcn_mfma_f32_16x16x32_bf16(a0, qf[kbk], st0, 0, 0, 0);
        st1 = __builtin_amdgcn_mfma_f32_16x16x32_bf16(a1, qf[kbk], st1, 0, 0, 0);
      }
      __builtin_amdgcn_s_setprio(0);

      const bool diag = (j0 + 31 > m0);
      float p[8];
      if (diag) {
        const int qrow = m0 + fr;
#pragma unroll
        for (int r = 0; r < 4; r++) {
          int c0 = j0 + quad * 4 + r;
          p[r]     = (c0      <= qrow) ? ex2(st0[r]) : 0.f;
          p[4 + r] = (c0 + 16 <= qrow) ? ex2(st1[r]) : 0.f;
        }
      } else {
#pragma unroll
        for (int r = 0; r < 4; r++) { p[r] = ex2(st0[r]); p[4 + r] = ex2(st1[r]); }
      }
      // packed words: A0={c0,c1} A1={c2,c3} (cols 0-15 over quads); B = cols 16-31
      unsigned A0 = pk2(p[0], p[1]), A1 = pk2(p[2], p[3]);
      unsigned B0 = pk2(p[4], p[5]), B1 = pk2(p[6], p[7]);
      unsigned alo0 = (unsigned)__builtin_amdgcn_ds_bpermute(idxf, (int)A0);
      unsigned alo1 = (unsigned)__builtin_amdgcn_ds_bpermute(idxf, (int)A1);
      unsigned ahi0 = (unsigned)__builtin_amdgcn_ds_bpermute(idxs, (int)A0);
      unsigned ahi1 = (unsigned)__builtin_amdgcn_ds_bpermute(idxs, (int)A1);
      unsigned blo0 = (unsigned)__builtin_amdgcn_ds_bpermute(idxf, (int)B0);
      unsigned blo1 = (unsigned)__builtin_amdgcn_ds_bpermute(idxf, (int)B1);
      unsigned bhi0 = (unsigned)__builtin_amdgcn_ds_bpermute(idxs, (int)B0);
      unsigned bhi1 = (unsigned)__builtin_amdgcn_ds_bpermute(idxs, (int)B1);
      const bool ql = (quad < 2);
      union { unsigned w[4]; v8bf v; } pw;
      pw.w[0] = ql ? alo0 : blo0;
      pw.w[1] = ql ? alo1 : blo1;
      pw.w[2] = ql ? ahi0 : bhi0;
      pw.w[3] = ql ? ahi1 : bhi1;
      v8bf pa = pw.v;

      // PV + l (V from registers)
      __builtin_amdgcn_s_setprio(1);
#pragma unroll
      for (int nt2 = 0; nt2 < 8; nt2++)
        oacc[nt2] = __builtin_amdgcn_mfma_f32_16x16x32_bf16(pa, vf[nt2], oacc[nt2], 0, 0, 0);
      lacc = __builtin_amdgcn_mfma_f32_16x16x32_bf16(pa, ones, lacc, 0, 0, 0);
      __builtin_amdgcn_s_setprio(0);
    }
    __syncthreads();
  }

  // partial write: rows m0 + quad*4 + r, col d = nt2*16 + fr
  unsigned short* Oc = Opart + (size_t)c * (NBH * TT * DD) + head_base;
#pragma unroll
  for (int nt2 = 0; nt2 < 8; nt2++)
#pragma unroll
    for (int r = 0; r < 4; r++)
      Oc[(size_t)(m0 + quad * 4 + r) * DD + nt2 * 16 + fr] = f2b(oacc[nt2][r]);
  if (fr == 0) {
#pragma unroll
    for (int r = 0; r < 4; r++)
      lpart[c * (NBH * TT) + bh * TT + m0 + quad * 4 + r] = lacc[r];
  }
}

// ---------------- combine: yb = (sum_c O_c)/(sum_c l_c), bf16 [bt][C] ----------
__global__ __launch_bounds__(256) void combine_kernel(const unsigned short* __restrict__ Opart,
                                                      const float* __restrict__ lpart,
                                                      unsigned short* __restrict__ yb) {
  int idx = blockIdx.x * 256 + threadIdx.x;    // 1,572,864 threads, 4 elems each
  int row = idx >> 5;                          // bh*2048 + t
  int dg = (idx & 31) * 4;
  int t = row & 2047;
  int qt = t >> 7;                             // 128-row blocks
  int nc = (4 * qt + 4 + 15) >> 4;             // chunks written for this row

  float a0 = 0.f, a1 = 0.f, a2 = 0.f, a3 = 0.f, l = 0.f;
  for (int cchunk = 0; cchunk < nc; cchunk++) {
    ushort4 o = *(const ushort4*)&Opart[(size_t)cchunk * (NBH * TT * DD) + (size_t)row * DD + dg];
    a0 += b2f(o.x); a1 += b2f(o.y); a2 += b2f(o.z); a3 += b2f(o.w);
    l += lpart[cchunk * (NBH * TT) + row];
  }
  float linv = 1.f / l;
  int bh = row >> 11;
  int b = bh / HH, h = bh % HH;
  ushort4 uo = { f2b(a0 * linv), f2b(a1 * linv), f2b(a2 * linv), f2b(a3 * linv) };
  *(ushort4*)&yb[((size_t)(b * TT + t)) * CC + h * DD + dg] = uo;
}

// ---------------- launch ----------------
extern "C" void kernel_launch(void* const* d_in, const int* in_sizes, int n_in,
                              void* d_out, int out_size, void* d_ws, size_t ws_size,
                              hipStream_t stream) {
  const float* x     = (const float*)d_in[0];
  const float* cosb  = (const float*)d_in[1];
  const float* sinb  = (const float*)d_in[2];
  const float* wq    = (const float*)d_in[3];
  const float* wk    = (const float*)d_in[4];
  const float* wv    = (const float*)d_in[5];
  const float* wproj = (const float*)d_in[6];
  float* out = (float*)d_out;

  // workspace layout (117,964,800 B exactly):
  //   0         : q_t bf16 [bh][t][d] (12,582,912)
  //   12582912  : k_t bf16 [bh][t][d] (12,582,912)
  //   25165824  : v2  bf16 repacked [bh][jt][nt2][lane][8] (12,582,912)
  //   37748736  : yb  bf16 [bt][C]    (12,582,912)
  //   50331648  : xb  bf16 (12,582,912) -> dead after gemm_qkv -> lpart (786,432)
  //   62914560  : wb  bf16 4x589824 elems (4,718,592)
  //   67633152  : Opart bf16 4 chunks x [bh][t][d] (50,331,648)
  char* w = (char*)d_ws;
  unsigned short* q_t   = (unsigned short*)(w);
  unsigned short* k_t   = (unsigned short*)(w + 12582912);
  unsigned short* v_t   = (unsigned short*)(w + 25165824);
  unsigned short* yb    = (unsigned short*)(w + 37748736);
  unsigned short* xb    = (unsigned short*)(w + 50331648);
  float*          lpart = (float*)(w + 50331648);   // alias xb (dead after gemm_qkv)
  unsigned short* wb    = (unsigned short*)(w + 62914560);
  unsigned short* Opart = (unsigned short*)(w + 67633152);

  cvt_all_kernel<<<8448, 256, 0, stream>>>(x, wq, wk, wv, wproj, xb, wb);

  gemm_qkv<<<dim3(BT / 128, 3 * HH), 256, 0, stream>>>(xb, wb, q_t, k_t, v_t);

  rope_all_kernel<<<24576, 256, 0, stream>>>(q_t, k_t, cosb, sinb);

  attn_mfma<<<1920, 256, 0, stream>>>(q_t, k_t, v_t, Opart, lpart);
  combine_kernel<<<6144, 256, 0, stream>>>(Opart, lpart, yb);

  gemm_w64<<<dim3(BT / 64, CC / 128), 256, 0, stream>>>(yb, wb + 3 * 589824, out);
}

// Round 8
// 232.431 us; speedup vs baseline: 1.2543x; 1.0349x over previous
//
#include <hip/hip_runtime.h>

// Problem constants (CausalSelfAttention: B=4 T=2048 C=768 H=KVH=6 D=128)
#define BB 4
#define TT 2048
#define CC 768
#define HH 6
#define DD 128
#define BT (BB * TT)          // 8192 rows
#define HALF 64
#define NBH (BB * HH)         // 24
// combined scale folded into q_t: exp(s/sqrt(128)) = exp2(s * QKSCALE)
#define QKSCALE 0.12753785627919282f   // (1/sqrt(128)) * log2(e)

typedef __bf16 v8bf __attribute__((ext_vector_type(8)));
typedef float f32x4 __attribute__((ext_vector_type(4)));

// ---------------- fp32 -> bf16 (RNE) ----------------
__device__ __forceinline__ unsigned short f2b(float f) {
  union { float f; unsigned u; } v; v.f = f;
  unsigned r = v.u + 0x7FFFu + ((v.u >> 16) & 1u);
  return (unsigned short)(r >> 16);
}
__device__ __forceinline__ float b2f(unsigned short u) {
  union { unsigned u; float f; } v; v.u = (unsigned)u << 16;
  return v.f;
}
// pack two fp32 -> bf16x2 by truncation: 1 v_perm_b32
__device__ __forceinline__ unsigned pk2(float f0, float f1) {
  union { float f; unsigned u; } a, b; a.f = f1; b.f = f0;
  return __builtin_amdgcn_perm(a.u, b.u, 0x07060302u);
}
// raw 2^x (v_exp_f32): inputs bounded (normed q/k), output feeds bf16
__device__ __forceinline__ float ex2(float x) {
  float r; asm("v_exp_f32 %0, %1" : "=v"(r) : "v"(x)); return r;
}

// async global->LDS, 16B per lane; lds base wave-uniform, deposit at base + lane*16
__device__ __forceinline__ void load_lds16(const void* g, void* l) {
  __builtin_amdgcn_global_load_lds(
      (const __attribute__((address_space(1))) unsigned int*)g,
      (__attribute__((address_space(3))) unsigned int*)(unsigned int)(unsigned long long)(l),
      16, 0, 0);
}

// ---------------- merged cvt: x (6144 blocks) + 4 weights (2304 blocks) -------
__global__ __launch_bounds__(256) void cvt_all_kernel(const float* __restrict__ x,
                                                      const float* __restrict__ w0,
                                                      const float* __restrict__ w1,
                                                      const float* __restrict__ w2,
                                                      const float* __restrict__ w3,
                                                      unsigned short* __restrict__ xb,
                                                      unsigned short* __restrict__ wb) {
  int bx = blockIdx.x;
  const float* src;
  unsigned short* dst;
  int i;
  if (bx < 6144) {
    src = x; dst = xb; i = bx * 256 + threadIdx.x;
  } else {
    int bsel = (bx - 6144) / 576;
    src = bsel == 0 ? w0 : bsel == 1 ? w1 : bsel == 2 ? w2 : w3;
    dst = wb + bsel * 589824;
    i = ((bx - 6144) % 576) * 256 + threadIdx.x;
  }
  float4 f = ((const float4*)src)[i];
  ushort4 o;
  o.x = f2b(f.x); o.y = f2b(f.y); o.z = f2b(f.z); o.w = f2b(f.w);
  ((ushort4*)dst)[i] = o;
}

// ---------------- fused QKV GEMM (128x128 tile, BK=32, dbuf + swizzled LDS) ----
// grid (64, 18): wsel = by/6 (0=q,1=k,2=v), head h = by%6.
// q,k -> bf16 [bh][t][d] (rope runs afterwards; k gets repacked there).
// v -> repacked PV-fragment order: V2[bh][jt][nt2][lane][8] (verified R7).
__global__ __launch_bounds__(256) void gemm_qkv(const unsigned short* __restrict__ A,
                                                const unsigned short* __restrict__ Wall,
                                                unsigned short* __restrict__ qb,
                                                unsigned short* __restrict__ kb,
                                                unsigned short* __restrict__ vt) {
  __shared__ __align__(16) unsigned short As[2][512 * 8];
  __shared__ __align__(16) unsigned short Bs[2][512 * 8];
  const int m0 = blockIdx.x * 128;
  const int wsel = blockIdx.y / HH, h = blockIdx.y % HH;
  const unsigned short* W = Wall + (size_t)wsel * 589824 + (size_t)h * 128 * CC;
  const int tid = threadIdx.x;
  const int wave = tid >> 6, lane = tid & 63;
  const int fr = lane & 15, quad = lane >> 4;
  const int wm = (wave & 1) * 64, wn = (wave >> 1) * 64;

  f32x4 acc[4][4];
#pragma unroll
  for (int i = 0; i < 4; i++)
#pragma unroll
    for (int j = 0; j < 4; j++) acc[i][j] = (f32x4){0.f, 0.f, 0.f, 0.f};

  auto stage = [&](int kk, int buf) {
#pragma unroll
    for (int it = 0; it < 2; it++) {
      int base_slot = wave * 128 + it * 64;
      int sigma = base_slot + lane;
      int r = sigma >> 2, g = (sigma & 3) ^ ((r >> 1) & 3);
      load_lds16(A + (size_t)(m0 + r) * CC + kk + g * 8, &As[buf][base_slot * 8]);
      load_lds16(W + (size_t)r * CC + kk + g * 8, &Bs[buf][base_slot * 8]);
    }
  };

  stage(0, 0);
  __syncthreads();
  for (int step = 0; step < CC / 32; step++) {
    int buf = step & 1;
    if (step + 1 < CC / 32) stage((step + 1) * 32, buf ^ 1);
    v8bf af[4], bfr[4];
#pragma unroll
    for (int i = 0; i < 4; i++) {
      int ra = wm + i * 16 + fr;
      af[i] = *(const v8bf*)&As[buf][(4 * ra + (quad ^ ((ra >> 1) & 3))) * 8];
      int rb = wn + i * 16 + fr;
      bfr[i] = *(const v8bf*)&Bs[buf][(4 * rb + (quad ^ ((rb >> 1) & 3))) * 8];
    }
#pragma unroll
    for (int i = 0; i < 4; i++)
#pragma unroll
      for (int j = 0; j < 4; j++)
        acc[i][j] = __builtin_amdgcn_mfma_f32_16x16x32_bf16(af[i], bfr[j], acc[i][j], 0, 0, 0);
    __syncthreads();
  }

  if (wsel < 2) {
    unsigned short* dst = wsel ? kb : qb;
#pragma unroll
    for (int i = 0; i < 4; i++) {
      int rr0 = m0 + wm + i * 16 + quad * 4;
      int b = rr0 >> 11, t0 = rr0 & 2047;
      size_t base = ((size_t)(b * HH + h) * TT + t0) * DD;
#pragma unroll
      for (int j = 0; j < 4; j++) {
        int d = wn + j * 16 + fr;
#pragma unroll
        for (int r = 0; r < 4; r++)
          dst[base + (size_t)r * DD + d] = f2b(acc[i][j][r]);
      }
    }
  } else {
#pragma unroll
    for (int i = 0; i < 4; i++) {
      int rr0 = m0 + wm + i * 16 + quad * 4;
      int b = rr0 >> 11, t0_ = rr0 & 2047;
      int bh = b * HH + h;
      int jt = t0_ >> 5;              // 32-row V tile
      int qv = (t0_ >> 3) & 3;        // quad slot within tile (const over r)
      int jj = t0_ & 7;               // elem start within lane group (0 or 4)
#pragma unroll
      for (int j = 0; j < 4; j++) {
        int d = wn + j * 16 + fr;
        int lane_v = qv * 16 + (d & 15);
        size_t off = ((size_t)(bh * 64 + jt) * 8 + (d >> 4)) * 512 + lane_v * 8 + jj;
        ushort4 u = { f2b(acc[i][j][0]), f2b(acc[i][j][1]),
                      f2b(acc[i][j][2]), f2b(acc[i][j][3]) };
        *(ushort4*)&vt[off] = u;
      }
    }
  }
}

// ---------------- wproj GEMM: 64x128 tile (768 blocks -> 3/CU) ----------------
__global__ __launch_bounds__(256) void gemm_w64(const unsigned short* __restrict__ A,
                                                const unsigned short* __restrict__ W,
                                                float* __restrict__ C) {
  __shared__ __align__(16) unsigned short As[2][256 * 8];
  __shared__ __align__(16) unsigned short Bs[2][512 * 8];
  const int m0 = blockIdx.x * 64, n0 = blockIdx.y * 128;
  const int tid = threadIdx.x;
  const int wave = tid >> 6, lane = tid & 63;
  const int fr = lane & 15, quad = lane >> 4;
  const int wm = (wave & 1) * 32, wn = (wave >> 1) * 64;

  f32x4 acc[2][4];
#pragma unroll
  for (int i = 0; i < 2; i++)
#pragma unroll
    for (int j = 0; j < 4; j++) acc[i][j] = (f32x4){0.f, 0.f, 0.f, 0.f};

  auto stage = [&](int kk, int buf) {
    {
      int base_slot = wave * 64;
      int sigma = base_slot + lane;
      int r = sigma >> 2, g = (sigma & 3) ^ ((r >> 1) & 3);
      load_lds16(A + (size_t)(m0 + r) * CC + kk + g * 8, &As[buf][base_slot * 8]);
    }
#pragma unroll
    for (int it = 0; it < 2; it++) {
      int base_slot = wave * 128 + it * 64;
      int sigma = base_slot + lane;
      int r = sigma >> 2, g = (sigma & 3) ^ ((r >> 1) & 3);
      load_lds16(W + (size_t)(n0 + r) * CC + kk + g * 8, &Bs[buf][base_slot * 8]);
    }
  };

  stage(0, 0);
  __syncthreads();
  for (int step = 0; step < CC / 32; step++) {
    int buf = step & 1;
    if (step + 1 < CC / 32) stage((step + 1) * 32, buf ^ 1);
    v8bf af[2], bfr[4];
#pragma unroll
    for (int i = 0; i < 2; i++) {
      int ra = wm + i * 16 + fr;
      af[i] = *(const v8bf*)&As[buf][(4 * ra + (quad ^ ((ra >> 1) & 3))) * 8];
    }
#pragma unroll
    for (int j = 0; j < 4; j++) {
      int rb = wn + j * 16 + fr;
      bfr[j] = *(const v8bf*)&Bs[buf][(4 * rb + (quad ^ ((rb >> 1) & 3))) * 8];
    }
#pragma unroll
    for (int i = 0; i < 2; i++)
#pragma unroll
      for (int j = 0; j < 4; j++)
        acc[i][j] = __builtin_amdgcn_mfma_f32_16x16x32_bf16(af[i], bfr[j], acc[i][j], 0, 0, 0);
    __syncthreads();
  }

  const int orow = m0 + wm + quad * 4;
#pragma unroll
  for (int i = 0; i < 2; i++)
#pragma unroll
    for (int j = 0; j < 4; j++) {
      int oc = n0 + wn + j * 16 + fr;
#pragma unroll
      for (int r = 0; r < 4; r++)
        C[(size_t)(orow + i * 16 + r) * CC + oc] = acc[i][j][r];
    }
}

// ---------------- RoPE + sample-var norm; q in place, k -> repacked K2 -------
// K2[bh][jt][kbk][half][lane][8]: lane=quad*16+fr, elem j holds
// k[t = jt*32 + half*16 + fr][d = kbk*32 + quad*8 + j] -- the exact QK^T
// A-operand fragment, so attn loads K with 1KB lane-contiguous instructions.
__global__ __launch_bounds__(256) void rope_all_kernel(unsigned short* __restrict__ qb,
                                                       const unsigned short* __restrict__ kb,
                                                       const float* __restrict__ cosb,
                                                       const float* __restrict__ sinb,
                                                       unsigned short* __restrict__ k2) {
  int bx = blockIdx.x;
  bool isq = (bx < 12288);
  const unsigned short* src = isq ? qb : kb;
  float scale = isq ? QKSCALE : 1.0f;
  int idx = (bx % 12288) * 4 + (threadIdx.x >> 6);   // bh*T + t
  int lane = threadIdx.x & 63;
  int tpos = idx & (TT - 1);
  size_t base = (size_t)idx * DD;

  float x1 = b2f(src[base + lane]);
  float x2 = b2f(src[base + HALF + lane]);
  float c = cosb[tpos * HALF + lane];
  float s = sinb[tpos * HALF + lane];
  float o1 = x1 * c + x2 * s;
  float o2 = x2 * c - x1 * s;

  float sum = o1 + o2;
#pragma unroll
  for (int off = 32; off; off >>= 1) sum += __shfl_xor(sum, off);
  float mean = sum * (1.f / 128.f);
  float d1 = o1 - mean, d2 = o2 - mean;
  float vs = d1 * d1 + d2 * d2;
#pragma unroll
  for (int off = 32; off; off >>= 1) vs += __shfl_xor(vs, off);
  float inv = scale / (sqrtf(vs * (1.f / 127.f)) + 1e-6f);

  if (isq) {
    qb[base + lane] = f2b(d1 * inv);
    qb[base + HALF + lane] = f2b(d2 * inv);
  } else {
    int bh = idx >> 11, t = idx & 2047;
    int jt = t >> 5, rr = t & 31;
    int half = rr >> 4, frv = rr & 15;
    int q5 = (lane >> 3) & 3, j = lane & 7, kb1 = lane >> 5;   // d=lane / d=lane+64
    size_t b2 = (size_t)bh * 262144 + (size_t)jt * 4096 + half * 512 + q5 * 128 + frv * 8 + j;
    k2[b2 + (size_t)kb1 * 1024] = f2b(d1 * inv);         // d = lane       (kbk = kb1)
    k2[b2 + (size_t)(kb1 + 2) * 1024] = f2b(d2 * inv);   // d = lane + 64  (kbk = kb1+2)
  }
}

// ---------------- MFMA flash attention v11: no LDS, no barriers --------------
// R5-R7 autopsy: per-block-iter wall ~3400cyc vs ~500cyc critical path -- the
// __syncthreads after each K-tile forces s_waitcnt vmcnt(0), draining the
// prefetch 25K times with only ~2 blocks/CU of cover. v11 deletes the shared
// state entirely: K repacked by rope (K2) like V (V2, R7-verified), so each
// wave loads its own K/V fragments straight from L2 with 1KB coalesced
// instructions -- counted vmcnt waits only, zero barriers, waves fully
// decoupled. 32-row waves (R0's verified 40-unit LPT split-K mapping, 960
// blocks, identical Opart/lpart/combine semantics). Per-XCD KV working set
// 3MB < 4MB L2. bpermute softmax redistribution unchanged (R2-verified).
__global__ __launch_bounds__(256) void attn_mfma(const unsigned short* __restrict__ qtb,
                                                 const unsigned short* __restrict__ k2b,
                                                 const unsigned short* __restrict__ v2b,
                                                 unsigned short* __restrict__ Opart,
                                                 float* __restrict__ lpart) {
  const int u = blockIdx.x;
  const int bh = u % NBH;
  const int uu = u / NBH;                         // 0..39, heavy-first
  int qt, c;
  if (uu < 16)      { qt = 15 - (uu >> 2); c = uu & 3; }
  else if (uu < 28) { int k = uu - 16; int q3 = k / 3; qt = 11 - q3; c = k - q3 * 3; }
  else if (uu < 36) { int k = uu - 28; qt = 7 - (k >> 1); c = k & 1; }
  else              { qt = 3 - (uu - 36); c = 0; }
  const int t0 = c * 16;
  const int t1 = min(t0 + 16, 4 * qt + 4);
  const int niter = t1 - t0;

  const int tid = threadIdx.x;
  const int wave = tid >> 6, lane = tid & 63;
  const int fr = lane & 15, quad = lane >> 4;
  const int idxf = 4 * ((quad & 1) * 32 + fr);    // bpermute byte idx, first src quad
  const int idxs = idxf + 64;                     // second src quad (+16 lanes)
  const size_t head_base = (size_t)bh * TT * DD;
  const int m0 = qt * 128 + wave * 32;            // wave's 32 Q rows

  const unsigned short* k2h = k2b + (size_t)bh * 262144;
  const unsigned short* v2h = v2b + (size_t)bh * 262144;

  v8bf qf[2][4];
#pragma unroll
  for (int qs = 0; qs < 2; qs++)
#pragma unroll
    for (int kbk = 0; kbk < 4; kbk++)
      qf[qs][kbk] = *(const v8bf*)(qtb + head_base +
                                   (size_t)(m0 + qs * 16 + fr) * DD + kbk * 32 + quad * 8);

  const __bf16 one_bf = (__bf16)1.0f;
  v8bf ones = {one_bf, one_bf, one_bf, one_bf, one_bf, one_bf, one_bf, one_bf};

  f32x4 oacc[2][8];
#pragma unroll
  for (int qs = 0; qs < 2; qs++)
#pragma unroll
    for (int i = 0; i < 8; i++) oacc[qs][i] = (f32x4){0.f, 0.f, 0.f, 0.f};
  f32x4 lacc[2] = {(f32x4){0.f, 0.f, 0.f, 0.f}, (f32x4){0.f, 0.f, 0.f, 0.f}};

  for (int it = 0; it < niter; it++) {
    const int jt = t0 + it;
    const int j0 = jt * 32;
    if (j0 > m0 + 31) continue;      // wave-uniform; no barriers anywhere

    // K fragments (kf[kbk*2+half]) then V fragments -- 16 coalesced 1KB loads;
    // QK waits on kf via counted vmcnt(8), vf arrive under QK+softmax.
    const unsigned short* kp = k2h + (size_t)jt * 4096 + lane * 8;
    v8bf kf[8];
#pragma unroll
    for (int i = 0; i < 8; i++) kf[i] = *(const v8bf*)&kp[i * 512];
    const unsigned short* vp = v2h + (size_t)jt * 4096 + lane * 8;
    v8bf vf[8];
#pragma unroll
    for (int i = 0; i < 8; i++) vf[i] = *(const v8bf*)&vp[i * 512];

    // S^T: D[m = K-col][n = Q-row]; K-frags shared across both qs sets
    f32x4 st[2][2];
#pragma unroll
    for (int qs = 0; qs < 2; qs++) { st[qs][0] = (f32x4){0,0,0,0}; st[qs][1] = (f32x4){0,0,0,0}; }
    __builtin_amdgcn_s_setprio(1);
#pragma unroll
    for (int kbk = 0; kbk < 4; kbk++) {
      st[0][0] = __builtin_amdgcn_mfma_f32_16x16x32_bf16(kf[kbk * 2],     qf[0][kbk], st[0][0], 0, 0, 0);
      st[0][1] = __builtin_amdgcn_mfma_f32_16x16x32_bf16(kf[kbk * 2 + 1], qf[0][kbk], st[0][1], 0, 0, 0);
      st[1][0] = __builtin_amdgcn_mfma_f32_16x16x32_bf16(kf[kbk * 2],     qf[1][kbk], st[1][0], 0, 0, 0);
      st[1][1] = __builtin_amdgcn_mfma_f32_16x16x32_bf16(kf[kbk * 2 + 1], qf[1][kbk], st[1][1], 0, 0, 0);
    }
    __builtin_amdgcn_s_setprio(0);

    const bool diag = (j0 + 31 > m0);   // at most 1 tile per wave (uniform)
    v8bf pa0, pa1;
#pragma unroll
    for (int qs = 0; qs < 2; qs++) {
      float p[8];
      if (diag) {
        const int qrow = m0 + qs * 16 + fr;
#pragma unroll
        for (int r = 0; r < 4; r++) {
          int c0 = j0 + quad * 4 + r;
          p[r]     = (c0      <= qrow) ? ex2(st[qs][0][r]) : 0.f;
          p[4 + r] = (c0 + 16 <= qrow) ? ex2(st[qs][1][r]) : 0.f;
        }
      } else {
#pragma unroll
        for (int r = 0; r < 4; r++) { p[r] = ex2(st[qs][0][r]); p[4 + r] = ex2(st[qs][1][r]); }
      }
      unsigned A0 = pk2(p[0], p[1]), A1 = pk2(p[2], p[3]);
      unsigned B0 = pk2(p[4], p[5]), B1 = pk2(p[6], p[7]);
      unsigned alo0 = (unsigned)__builtin_amdgcn_ds_bpermute(idxf, (int)A0);
      unsigned alo1 = (unsigned)__builtin_amdgcn_ds_bpermute(idxf, (int)A1);
      unsigned ahi0 = (unsigned)__builtin_amdgcn_ds_bpermute(idxs, (int)A0);
      unsigned ahi1 = (unsigned)__builtin_amdgcn_ds_bpermute(idxs, (int)A1);
      unsigned blo0 = (unsigned)__builtin_amdgcn_ds_bpermute(idxf, (int)B0);
      unsigned blo1 = (unsigned)__builtin_amdgcn_ds_bpermute(idxf, (int)B1);
      unsigned bhi0 = (unsigned)__builtin_amdgcn_ds_bpermute(idxs, (int)B0);
      unsigned bhi1 = (unsigned)__builtin_amdgcn_ds_bpermute(idxs, (int)B1);
      const bool ql = (quad < 2);
      union { unsigned w[4]; v8bf v; } pw;
      pw.w[0] = ql ? alo0 : blo0;
      pw.w[1] = ql ? alo1 : blo1;
      pw.w[2] = ql ? ahi0 : bhi0;
      pw.w[3] = ql ? ahi1 : bhi1;
      if (qs == 0) pa0 = pw.v; else pa1 = pw.v;
    }

    // PV + l (V from registers)
    __builtin_amdgcn_s_setprio(1);
#pragma unroll
    for (int nt2 = 0; nt2 < 8; nt2++) {
      oacc[0][nt2] = __builtin_amdgcn_mfma_f32_16x16x32_bf16(pa0, vf[nt2], oacc[0][nt2], 0, 0, 0);
      oacc[1][nt2] = __builtin_amdgcn_mfma_f32_16x16x32_bf16(pa1, vf[nt2], oacc[1][nt2], 0, 0, 0);
    }
    lacc[0] = __builtin_amdgcn_mfma_f32_16x16x32_bf16(pa0, ones, lacc[0], 0, 0, 0);
    lacc[1] = __builtin_amdgcn_mfma_f32_16x16x32_bf16(pa1, ones, lacc[1], 0, 0, 0);
    __builtin_amdgcn_s_setprio(0);
  }

  // partial write: rows m0 + qs*16 + quad*4 + r, col d = nt2*16 + fr
  unsigned short* Oc = Opart + (size_t)c * (NBH * TT * DD) + head_base;
#pragma unroll
  for (int qs = 0; qs < 2; qs++) {
#pragma unroll
    for (int nt2 = 0; nt2 < 8; nt2++)
#pragma unroll
      for (int r = 0; r < 4; r++)
        Oc[(size_t)(m0 + qs * 16 + quad * 4 + r) * DD + nt2 * 16 + fr] = f2b(oacc[qs][nt2][r]);
    if (fr == 0) {
#pragma unroll
      for (int r = 0; r < 4; r++)
        lpart[c * (NBH * TT) + bh * TT + m0 + qs * 16 + quad * 4 + r] = lacc[qs][r];
    }
  }
}

// ---------------- combine: yb = (sum_c O_c)/(sum_c l_c), bf16 [bt][C] ----------
__global__ __launch_bounds__(256) void combine_kernel(const unsigned short* __restrict__ Opart,
                                                      const float* __restrict__ lpart,
                                                      unsigned short* __restrict__ yb) {
  int idx = blockIdx.x * 256 + threadIdx.x;    // 1,572,864 threads, 4 elems each
  int row = idx >> 5;                          // bh*2048 + t
  int dg = (idx & 31) * 4;
  int t = row & 2047;
  int qt = t >> 7;                             // 128-row blocks
  int nc = (4 * qt + 4 + 15) >> 4;             // chunks written for this row

  float a0 = 0.f, a1 = 0.f, a2 = 0.f, a3 = 0.f, l = 0.f;
  for (int cchunk = 0; cchunk < nc; cchunk++) {
    ushort4 o = *(const ushort4*)&Opart[(size_t)cchunk * (NBH * TT * DD) + (size_t)row * DD + dg];
    a0 += b2f(o.x); a1 += b2f(o.y); a2 += b2f(o.z); a3 += b2f(o.w);
    l += lpart[cchunk * (NBH * TT) + row];
  }
  float linv = 1.f / l;
  int bh = row >> 11;
  int b = bh / HH, h = bh % HH;
  ushort4 uo = { f2b(a0 * linv), f2b(a1 * linv), f2b(a2 * linv), f2b(a3 * linv) };
  *(ushort4*)&yb[((size_t)(b * TT + t)) * CC + h * DD + dg] = uo;
}

// ---------------- launch ----------------
extern "C" void kernel_launch(void* const* d_in, const int* in_sizes, int n_in,
                              void* d_out, int out_size, void* d_ws, size_t ws_size,
                              hipStream_t stream) {
  const float* x     = (const float*)d_in[0];
  const float* cosb  = (const float*)d_in[1];
  const float* sinb  = (const float*)d_in[2];
  const float* wq    = (const float*)d_in[3];
  const float* wk    = (const float*)d_in[4];
  const float* wv    = (const float*)d_in[5];
  const float* wproj = (const float*)d_in[6];
  float* out = (float*)d_out;

  // workspace layout (117,964,800 B exactly):
  //   0         : q_t bf16 [bh][t][d] (12,582,912)
  //   12582912  : k_t bf16 [bh][t][d] (12,582,912) -> dead after rope -> lpart (786,432)
  //   25165824  : v2  bf16 repacked [bh][jt][nt2][lane][8] (12,582,912)
  //   37748736  : yb  bf16 [bt][C]    (12,582,912)
  //   50331648  : xb  bf16 (12,582,912) -> dead after gemm_qkv -> K2 repacked (12,582,912)
  //   62914560  : wb  bf16 4x589824 elems (4,718,592)
  //   67633152  : Opart bf16 4 chunks x [bh][t][d] (50,331,648)
  char* w = (char*)d_ws;
  unsigned short* q_t   = (unsigned short*)(w);
  unsigned short* k_t   = (unsigned short*)(w + 12582912);
  float*          lpart = (float*)(w + 12582912);   // alias k_t (dead after rope)
  unsigned short* v_t   = (unsigned short*)(w + 25165824);
  unsigned short* yb    = (unsigned short*)(w + 37748736);
  unsigned short* xb    = (unsigned short*)(w + 50331648);
  unsigned short* K2    = (unsigned short*)(w + 50331648);  // alias xb (dead after gemm_qkv)
  unsigned short* wb    = (unsigned short*)(w + 62914560);
  unsigned short* Opart = (unsigned short*)(w + 67633152);

  cvt_all_kernel<<<8448, 256, 0, stream>>>(x, wq, wk, wv, wproj, xb, wb);

  gemm_qkv<<<dim3(BT / 128, 3 * HH), 256, 0, stream>>>(xb, wb, q_t, k_t, v_t);

  rope_all_kernel<<<24576, 256, 0, stream>>>(q_t, k_t, cosb, sinb, K2);

  attn_mfma<<<960, 256, 0, stream>>>(q_t, K2, v_t, Opart, lpart);
  combine_kernel<<<6144, 256, 0, stream>>>(Opart, lpart, yb);

  gemm_w64<<<dim3(BT / 64, CC / 128), 256, 0, stream>>>(yb, wb + 3 * 589824, out);
}